// Round 1
// 53.635 us; speedup vs baseline: 1.0007x; 1.0007x over previous
//
#include <hip/hip_runtime.h>
#include <math.h>

// 4-qubit statevector simulator, fully real arithmetic.
// Optimizations vs previous version:
//  - Constant prefix (X0,X1,CNOT23,CNOT02,H3,H0,CNOT23,CNOT01) on |0000>
//    precomputed analytically: psi[6]=psi[7]=+0.5, psi[10]=psi[11]=-0.5.
//  - All 8 RY gates use angles +/- phi/8 -> a single sincosf(phi/16)
//    provides (c, s); RY(+th)=(c,-s;s,c), RY(-th)=(c,s;-s,c).

__device__ __forceinline__ void apply1(float* p, int w,
                                       float u00, float u01,
                                       float u10, float u11) {
    const int bit = 1 << (3 - w);
    #pragma unroll
    for (int i = 0; i < 16; ++i) {
        if (i & bit) continue;
        const float a = p[i];
        const float b = p[i | bit];
        p[i]        = u00 * a + u01 * b;
        p[i | bit]  = u10 * a + u11 * b;
    }
}

__device__ __forceinline__ void apply_h(float* p, int w) {
    const float s = 0.70710678118654752440f;
    apply1(p, w, s, s, s, -s);
}

// RY with precomputed c = cos(phi/16), s = sin(phi/16); sgn=+1 -> RY(+phi/8)
__device__ __forceinline__ void apply_ry_cs(float* p, int w, float c, float s) {
    apply1(p, w, c, -s, s, c);
}

__device__ __forceinline__ void apply_cnot(float* p, int c, int t) {
    const int cb = 1 << (3 - c);
    const int tb = 1 << (3 - t);
    #pragma unroll
    for (int i = 0; i < 16; ++i) {
        if ((i & cb) && !(i & tb)) {
            const float tmp = p[i];
            p[i]      = p[i | tb];
            p[i | tb] = tmp;
        }
    }
}

__global__ __launch_bounds__(64, 1)
void Model_35235911696437_kernel(const float* __restrict__ phi_p,
                                 float* __restrict__ out) {
    if (threadIdx.x != 0 || blockIdx.x != 0) return;

    const float phi = phi_p[0];
    const float t   = phi * 0.0625f;   // (phi/8)/2
    float s, c;
    sincosf(t, &s, &c);

    // State after the 8 constant prefix gates (hand-verified):
    //   |0000> --X0,X1,C23,C02--> |1110>
    //   --H3--> (|1110>+|1111>)/sqrt2
    //   --H0--> (|0110>-|1110>+|0111>-|1111>)/2
    //   --C23--> (|0111>+|0110>-|1111>-|1110>)/2   (invariant under the swap)
    //   --C01--> psi[6]=psi[7]=+0.5, psi[10]=psi[11]=-0.5
    float psi[16];
    #pragma unroll
    for (int i = 0; i < 16; ++i) psi[i] = 0.f;
    psi[6]  =  0.5f;
    psi[7]  =  0.5f;
    psi[10] = -0.5f;
    psi[11] = -0.5f;

    // --- remaining circuit (22 gates) ---
    apply_ry_cs(psi, 1,  c,  s);   // RY(+th) on q1
    apply_ry_cs(psi, 0,  c, -s);   // RY(-th) on q0
    apply_cnot(psi, 0, 3);
    apply_h(psi, 3);
    apply_cnot(psi, 3, 1);
    apply_ry_cs(psi, 1,  c,  s);
    apply_ry_cs(psi, 0,  c, -s);
    apply_cnot(psi, 2, 1);
    apply_cnot(psi, 2, 0);
    apply_ry_cs(psi, 1,  c, -s);   // RY(-th) on q1
    apply_ry_cs(psi, 0,  c,  s);   // RY(+th) on q0
    apply_cnot(psi, 3, 1);
    apply_h(psi, 3);
    apply_cnot(psi, 0, 3);
    apply_ry_cs(psi, 1,  c, -s);
    apply_ry_cs(psi, 0,  c,  s);
    apply_cnot(psi, 0, 1);
    apply_cnot(psi, 2, 0);
    apply_h(psi, 0);
    apply_h(psi, 3);
    apply_cnot(psi, 0, 2);
    apply_cnot(psi, 2, 3);

    // --- observables ---
    // wire w -> bit 1<<(3-w): w0->8, w1->4, w2->2, w3->1
    float res[14];

    float z0 = 0.f, z1 = 0.f, z2 = 0.f, z3 = 0.f;
    float z02 = 0.f, z13 = 0.f, z03 = 0.f, z12 = 0.f, z01 = 0.f, z23 = 0.f;
    #pragma unroll
    for (int i = 0; i < 16; ++i) {
        const float p2 = psi[i] * psi[i];
        const float s0 = (i & 8) ? -1.f : 1.f;
        const float s1 = (i & 4) ? -1.f : 1.f;
        const float s2 = (i & 2) ? -1.f : 1.f;
        const float s3 = (i & 1) ? -1.f : 1.f;
        z0 += s0 * p2;  z1 += s1 * p2;  z2 += s2 * p2;  z3 += s3 * p2;
        z02 += s0 * s2 * p2;  z13 += s1 * s3 * p2;
        z03 += s0 * s3 * p2;  z12 += s1 * s2 * p2;
        z01 += s0 * s1 * p2;  z23 += s2 * s3 * p2;
    }
    res[0] = z2;  res[1] = z3;  res[2] = z0;  res[3] = z1;
    res[4] = z02; res[5] = z13; res[6] = z03; res[7] = z12;
    res[8] = z01; res[9] = z23;

    // 4-qubit strings: flip all bits (mask 15); two Y's each:
    // (i*s_a)(i*s_b) = -s_a*s_b, s_w(j) = +1 if bit set else -1.
    float yyxx = 0.f, xxyy = 0.f, yxxy = 0.f, xyyx = 0.f;
    #pragma unroll
    for (int j = 0; j < 16; ++j) {
        const float s0 = (j & 8) ? 1.f : -1.f;
        const float s1 = (j & 4) ? 1.f : -1.f;
        const float s2 = (j & 2) ? 1.f : -1.f;
        const float s3 = (j & 1) ? 1.f : -1.f;
        const float prod = psi[j] * psi[j ^ 15];
        yyxx += -s0 * s1 * prod;   // Y on wires 0,1
        xxyy += -s2 * s3 * prod;   // Y on wires 2,3
        yxxy += -s0 * s3 * prod;   // Y on wires 0,3
        xyyx += -s1 * s2 * prod;   // Y on wires 1,2
    }
    res[10] = yyxx; res[11] = xxyy; res[12] = yxxy; res[13] = xyyx;

    const float coeffs[14] = {
        -0.24274501260941383f, -0.24274501260941383f,
         0.1777135822909176f,   0.1777135822909176f,
         0.12293330449299354f,  0.12293330449299354f,
         0.1676833885560135f,   0.1676833885560135f,
         0.17059759276836806f,  0.17627661394181787f,
        -0.04475008406301996f, -0.04475008406301996f,
         0.04475008406301996f,  0.04475008406301996f };

    float energy = -0.042072551947440084f;
    #pragma unroll
    for (int k = 0; k < 14; ++k) energy += coeffs[k] * res[k];

    out[0] = energy;
}

extern "C" void kernel_launch(void* const* d_in, const int* in_sizes, int n_in,
                              void* d_out, int out_size, void* d_ws, size_t ws_size,
                              hipStream_t stream) {
    (void)in_sizes; (void)n_in; (void)d_ws; (void)ws_size; (void)out_size;
    const float* phi = (const float*)d_in[0];
    float* out = (float*)d_out;
    Model_35235911696437_kernel<<<1, 64, 0, stream>>>(phi, out);
}